// Round 1
// baseline (249.269 us; speedup 1.0000x reference)
//
#include <hip/hip_runtime.h>
#include <math.h>

// Closed form derived from the reference:
//   q[n,0] = prod_{v=1..7} cos(x[n,v]+theta[v])
//   q[n,w] = prod_{v=0..w} cos(x[n,v]+theta[v])   (w = 1..7)
// (CNOT ring is GF(2)-linear; Z-expectations of a product measure factor
//  into cos(phi) over the parity sets S_0={1..7}, S_w={0..w}.)
// Then plain S^2 attention with E=8, no-max softmax (scores bounded by 8/sqrt2),
// output scramble: final[b,r,k] = sum_c att[b,(r%512)*8+c, r/512] * W[k,c] + bias[k].

#define NWIRES 8
#define SEQ    4096
#define NBATCH 16
#define TPB    256
#define HALF   2048   // rows of q staged in LDS per phase (64 KB)

__global__ __launch_bounds__(TPB, 1)
void qattn_kernel(const float* __restrict__ x, const float* __restrict__ theta,
                  const float* __restrict__ wc, const float* __restrict__ bc,
                  float* __restrict__ out)
{
    __shared__ float ldsq[HALF * NWIRES];   // 65536 B
    const int tid = threadIdx.x;
    const int b   = blockIdx.x >> 4;          // 16 s-chunks per batch
    const int S0  = (blockIdx.x & 15) * TPB;  // this block's s range

    float th[8];
#pragma unroll
    for (int w = 0; w < 8; ++w) th[w] = theta[w];

    const float* xb = x + ((size_t)b * SEQ) * NWIRES;

    // ---- own row q_s, pre-scaled by 1/sqrt(d_k) = 1/sqrt(2) ----
    const int s = S0 + tid;
    float qs[8];
    {
        const float4 xa  = *(const float4*)(xb + s * 8);
        const float4 xb4 = *(const float4*)(xb + s * 8 + 4);
        float c0 = __cosf(xa.x  + th[0]);
        float c1 = __cosf(xa.y  + th[1]);
        float c2 = __cosf(xa.z  + th[2]);
        float c3 = __cosf(xa.w  + th[3]);
        float c4 = __cosf(xb4.x + th[4]);
        float c5 = __cosf(xb4.y + th[5]);
        float c6 = __cosf(xb4.z + th[6]);
        float c7 = __cosf(xb4.w + th[7]);
        qs[1] = c0 * c1;
        qs[2] = qs[1] * c2;
        qs[3] = qs[2] * c3;
        qs[4] = qs[3] * c4;
        qs[5] = qs[4] * c5;
        qs[6] = qs[5] * c6;
        qs[7] = qs[6] * c7;
        qs[0] = c1 * c2 * c3 * c4 * c5 * c6 * c7;
        const float scale = 0.70710678118654752f;
#pragma unroll
        for (int w = 0; w < 8; ++w) qs[w] *= scale;
    }

    float acc[8] = {0.f, 0.f, 0.f, 0.f, 0.f, 0.f, 0.f, 0.f};
    float ssum = 0.f;

    for (int half = 0; half < 2; ++half) {
        __syncthreads();   // protect LDS from previous phase's readers
        const int T0 = half * HALF;
        // stage q rows [T0, T0+HALF) into LDS (computed on the fly; cheap)
#pragma unroll
        for (int k = 0; k < HALF / TPB; ++k) {
            const int tt = tid + k * TPB;
            const int t  = T0 + tt;
            const float4 xa  = *(const float4*)(xb + t * 8);
            const float4 xb4 = *(const float4*)(xb + t * 8 + 4);
            float c0 = __cosf(xa.x  + th[0]);
            float c1 = __cosf(xa.y  + th[1]);
            float c2 = __cosf(xa.z  + th[2]);
            float c3 = __cosf(xa.w  + th[3]);
            float c4 = __cosf(xb4.x + th[4]);
            float c5 = __cosf(xb4.y + th[5]);
            float c6 = __cosf(xb4.z + th[6]);
            float c7 = __cosf(xb4.w + th[7]);
            float q1 = c0 * c1;
            float q2 = q1 * c2;
            float q3 = q2 * c3;
            float q4 = q3 * c4;
            float q5 = q4 * c5;
            float q6 = q5 * c6;
            float q7 = q6 * c7;
            float q0 = c1 * c2 * c3 * c4 * c5 * c6 * c7;
            float4* dst = (float4*)(ldsq + tt * 8);
            dst[0] = make_float4(q0, q1, q2, q3);
            dst[1] = make_float4(q4, q5, q6, q7);
        }
        __syncthreads();
        // main loop: wave-uniform broadcast reads from LDS, no-max softmax
#pragma unroll 4
        for (int tt = 0; tt < HALF; ++tt) {
            const float4 qa = *(const float4*)(ldsq + tt * 8);
            const float4 qb = *(const float4*)(ldsq + tt * 8 + 4);
            float dot = qs[0] * qa.x + qs[1] * qa.y + qs[2] * qa.z + qs[3] * qa.w
                      + qs[4] * qb.x + qs[5] * qb.y + qs[6] * qb.z + qs[7] * qb.w;
            float p = __expf(dot);
            ssum += p;
            acc[0] += p * qa.x;
            acc[1] += p * qa.y;
            acc[2] += p * qa.z;
            acc[3] += p * qa.w;
            acc[4] += p * qb.x;
            acc[5] += p * qb.y;
            acc[6] += p * qb.z;
            acc[7] += p * qb.w;
        }
    }

    const float inv = 1.0f / ssum;

    // ---- epilogue: resolve swapaxes/reshape scramble via LDS ----
    __syncthreads();
#pragma unroll
    for (int e = 0; e < 8; ++e) ldsq[tid * 8 + e] = acc[e] * inv;
    __syncthreads();

    // output row r = e*512 + S0/8 + i uses att[b, S0 + i*8 + c, e], c=0..7
    const int e = tid >> 5;
    const int i = tid & 31;
    const int r = e * 512 + (S0 >> 3) + i;
    float y[8];
#pragma unroll
    for (int c = 0; c < 8; ++c) y[c] = ldsq[(i * 8 + c) * 8 + e];
    float o[8];
#pragma unroll
    for (int k = 0; k < 8; ++k) {
        float a = bc[k];
#pragma unroll
        for (int c = 0; c < 8; ++c) a += y[c] * wc[k * 8 + c];
        o[k] = a;
    }
    float4* op = (float4*)(out + ((size_t)b * SEQ + r) * 8);
    op[0] = make_float4(o[0], o[1], o[2], o[3]);
    op[1] = make_float4(o[4], o[5], o[6], o[7]);
}

extern "C" void kernel_launch(void* const* d_in, const int* in_sizes, int n_in,
                              void* d_out, int out_size, void* d_ws, size_t ws_size,
                              hipStream_t stream)
{
    const float* x  = (const float*)d_in[0];
    const float* th = (const float*)d_in[1];
    const float* wc = (const float*)d_in[2];
    const float* bc = (const float*)d_in[3];
    float* out = (float*)d_out;

    qattn_kernel<<<dim3(NBATCH * (SEQ / TPB)), dim3(TPB), 0, stream>>>(x, th, wc, bc, out);
}

// Round 2
// 173.264 us; speedup vs baseline: 1.4387x; 1.4387x over previous
//
#include <hip/hip_runtime.h>
#include <math.h>

// Closed form derived from the reference:
//   q[n,0] = prod_{v=1..7} cos(x[n,v]+theta[v])
//   q[n,w] = prod_{v=0..w} cos(x[n,v]+theta[v])   (w = 1..7)
// (CNOT ring is GF(2)-linear; Z-expectations of a product measure factor.)
// Attention with E=8, no-max softmax (|score| <= 8/sqrt2), output scramble:
//   final[b,r,k] = sum_c att[b,(r%512)*8+c, r/512] * W[k,c] + bias[k].
//
// R1: TPB=1024, 4-way t-split per block (g=tid>>8) -> 16 waves/CU instead of 4;
//     packed-fp32 inner loop (v_pk_fma_f32) to halve FMA instruction count.

#define NWIRES 8
#define SEQ    4096
#define NBATCH 16
#define ROWS   256    // s-rows per block
#define TPB    1024   // 4 t-groups x ROWS
#define HALF   2048   // q rows staged in LDS per phase (64 KB)
#define TQ     512    // t-iters per thread per phase (HALF/4)

typedef float v2f __attribute__((ext_vector_type(2)));

__global__ __launch_bounds__(TPB)
void qattn_kernel(const float* __restrict__ x, const float* __restrict__ theta,
                  const float* __restrict__ wc, const float* __restrict__ bc,
                  float* __restrict__ out)
{
    __shared__ float ldsq[HALF * NWIRES];   // 65536 B; re-used for partials+scramble
    float* part = ldsq;                      // [TPB][9] = 36864 B (after main loop)
    float* attn = ldsq + TPB * 9;            // [ROWS][8] = 8192 B (ends at 45056 B)

    const int tid = threadIdx.x;
    const int r   = tid & (ROWS - 1);        // local s-row
    const int g   = tid >> 8;                // t-group (wave-uniform)
    const int b   = blockIdx.x >> 4;
    const int S0  = (blockIdx.x & 15) * ROWS;

    float th[8];
#pragma unroll
    for (int w = 0; w < 8; ++w) th[w] = theta[w];

    const float* xb = x + ((size_t)b * SEQ) * NWIRES;

    // ---- own row q_s, pre-scaled by 1/sqrt(2) ----
    const int s = S0 + r;
    v2f q01, q23, q45, q67;
    {
        const float4 xa  = *(const float4*)(xb + s * 8);
        const float4 xb4 = *(const float4*)(xb + s * 8 + 4);
        float c0 = __cosf(xa.x  + th[0]);
        float c1 = __cosf(xa.y  + th[1]);
        float c2 = __cosf(xa.z  + th[2]);
        float c3 = __cosf(xa.w  + th[3]);
        float c4 = __cosf(xb4.x + th[4]);
        float c5 = __cosf(xb4.y + th[5]);
        float c6 = __cosf(xb4.z + th[6]);
        float c7 = __cosf(xb4.w + th[7]);
        float q1 = c0 * c1;
        float q2 = q1 * c2;
        float q3 = q2 * c3;
        float q4 = q3 * c4;
        float q5 = q4 * c5;
        float q6 = q5 * c6;
        float q7 = q6 * c7;
        float q0 = c1 * c2 * c3 * c4 * c5 * c6 * c7;
        const float sc = 0.70710678118654752f;
        q01 = (v2f){q0 * sc, q1 * sc};
        q23 = (v2f){q2 * sc, q3 * sc};
        q45 = (v2f){q4 * sc, q5 * sc};
        q67 = (v2f){q6 * sc, q7 * sc};
    }

    v2f a01 = {0.f, 0.f}, a23 = {0.f, 0.f}, a45 = {0.f, 0.f}, a67 = {0.f, 0.f};
    float ssum = 0.f;

    for (int half = 0; half < 2; ++half) {
        __syncthreads();   // protect LDS from previous phase's readers
        const int T0 = half * HALF;
        // stage q rows [T0, T0+HALF) into LDS: 1024 threads x 2 rows
#pragma unroll
        for (int k = 0; k < HALF / TPB; ++k) {
            const int tt = tid + k * TPB;
            const int t  = T0 + tt;
            const float4 xa  = *(const float4*)(xb + t * 8);
            const float4 xb4 = *(const float4*)(xb + t * 8 + 4);
            float c0 = __cosf(xa.x  + th[0]);
            float c1 = __cosf(xa.y  + th[1]);
            float c2 = __cosf(xa.z  + th[2]);
            float c3 = __cosf(xa.w  + th[3]);
            float c4 = __cosf(xb4.x + th[4]);
            float c5 = __cosf(xb4.y + th[5]);
            float c6 = __cosf(xb4.z + th[6]);
            float c7 = __cosf(xb4.w + th[7]);
            float q1 = c0 * c1;
            float q2 = q1 * c2;
            float q3 = q2 * c3;
            float q4 = q3 * c4;
            float q5 = q4 * c5;
            float q6 = q5 * c6;
            float q7 = q6 * c7;
            float q0 = c1 * c2 * c3 * c4 * c5 * c6 * c7;
            float4* dst = (float4*)(ldsq + tt * 8);
            dst[0] = make_float4(q0, q1, q2, q3);
            dst[1] = make_float4(q4, q5, q6, q7);
        }
        __syncthreads();
        // group g consumes staged rows [g*TQ, (g+1)*TQ): wave-uniform broadcast
        const float* base = ldsq + g * TQ * 8;
#pragma unroll 4
        for (int tt = 0; tt < TQ; ++tt) {
            const float4 qa = *(const float4*)(base + tt * 8);
            const float4 qb = *(const float4*)(base + tt * 8 + 4);
            v2f t0 = {qa.x, qa.y}, t1 = {qa.z, qa.w};
            v2f t2 = {qb.x, qb.y}, t3 = {qb.z, qb.w};
            v2f d = q01 * t0;
            d = __builtin_elementwise_fma(q23, t1, d);
            d = __builtin_elementwise_fma(q45, t2, d);
            d = __builtin_elementwise_fma(q67, t3, d);
            float p = __expf(d.x + d.y);
            ssum += p;
            v2f pv = {p, p};
            a01 = __builtin_elementwise_fma(pv, t0, a01);
            a23 = __builtin_elementwise_fma(pv, t1, a23);
            a45 = __builtin_elementwise_fma(pv, t2, a45);
            a67 = __builtin_elementwise_fma(pv, t3, a67);
        }
    }

    // ---- combine the 4 t-group partials through LDS ----
    __syncthreads();                       // main-loop readers done; reuse LDS
    {
        float* p9 = part + tid * 9;        // stride 9: coprime with 32 banks
        p9[0] = a01.x; p9[1] = a01.y; p9[2] = a23.x; p9[3] = a23.y;
        p9[4] = a45.x; p9[5] = a45.y; p9[6] = a67.x; p9[7] = a67.y;
        p9[8] = ssum;
    }
    __syncthreads();
    if (tid < ROWS) {
        float acc[8] = {0, 0, 0, 0, 0, 0, 0, 0};
        float sm = 0.f;
#pragma unroll
        for (int gg = 0; gg < 4; ++gg) {
            const float* p9 = part + (gg * ROWS + tid) * 9;
#pragma unroll
            for (int j = 0; j < 8; ++j) acc[j] += p9[j];
            sm += p9[8];
        }
        const float inv = 1.0f / sm;
#pragma unroll
        for (int j = 0; j < 8; ++j) attn[tid * 8 + j] = acc[j] * inv;
    }
    __syncthreads();

    // ---- epilogue: resolve swapaxes/reshape scramble ----
    if (tid < ROWS) {
        const int e = tid >> 5;
        const int i = tid & 31;
        const int rr = e * 512 + (S0 >> 3) + i;
        float y[8];
#pragma unroll
        for (int c = 0; c < 8; ++c) y[c] = attn[(i * 8 + c) * 8 + e];
        float o[8];
#pragma unroll
        for (int k = 0; k < 8; ++k) {
            float a = bc[k];
#pragma unroll
            for (int c = 0; c < 8; ++c) a += y[c] * wc[k * 8 + c];
            o[k] = a;
        }
        float4* op = (float4*)(out + ((size_t)b * SEQ + rr) * 8);
        op[0] = make_float4(o[0], o[1], o[2], o[3]);
        op[1] = make_float4(o[4], o[5], o[6], o[7]);
    }
}

extern "C" void kernel_launch(void* const* d_in, const int* in_sizes, int n_in,
                              void* d_out, int out_size, void* d_ws, size_t ws_size,
                              hipStream_t stream)
{
    const float* x  = (const float*)d_in[0];
    const float* th = (const float*)d_in[1];
    const float* wc = (const float*)d_in[2];
    const float* bc = (const float*)d_in[3];
    float* out = (float*)d_out;

    qattn_kernel<<<dim3(NBATCH * (SEQ / ROWS)), dim3(TPB), 0, stream>>>(x, th, wc, bc, out);
}

// Round 4
// 172.998 us; speedup vs baseline: 1.4409x; 1.0015x over previous
//
#include <hip/hip_runtime.h>
#include <math.h>

// Closed form derived from the reference:
//   q[n,0] = prod_{v=1..7} cos(x[n,v]+theta[v])
//   q[n,w] = prod_{v=0..w} cos(x[n,v]+theta[v])   (w = 1..7)
// (CNOT ring is GF(2)-linear; Z-expectations of a product measure factor.)
// Attention with E=8, no-max softmax (|score| <= 8/sqrt2), output scramble:
//   final[b,r,k] = sum_c att[b,(r%512)*8+c, r/512] * W[k,c] + bias[k].
//
// R3: R2 with the broadcast-FMA fixed — v_pk_fma_f32 needs all operands as
//     even-aligned VGPR pairs, so p is materialized as {p,p} (1-2 movs/iter).

#define NWIRES 8
#define SEQ    4096
#define NBATCH 16
#define ROWS   128    // distinct s-rows per block
#define GRP    8      // t-split groups
#define TPB    1024   // GRP * ROWS
#define HALF   2048   // q rows staged in LDS per phase (64 KB)
#define TQ     (HALF / GRP)   // 256 t-iters per thread per phase

typedef float v2f __attribute__((ext_vector_type(2)));

static __device__ __forceinline__ v2f pk_mul(v2f a, v2f b) {
    v2f d; asm("v_pk_mul_f32 %0, %1, %2" : "=v"(d) : "v"(a), "v"(b)); return d;
}
static __device__ __forceinline__ v2f pk_fma(v2f a, v2f b, v2f c) {
    v2f d; asm("v_pk_fma_f32 %0, %1, %2, %3" : "=v"(d) : "v"(a), "v"(b), "v"(c)); return d;
}

#if __has_builtin(__builtin_amdgcn_exp2f)
#define EXP2F(x) __builtin_amdgcn_exp2f(x)
#else
#define EXP2F(x) __expf((x) * 0.69314718055994531f)
#endif

__global__ __launch_bounds__(TPB, 8)   // 8 waves/EU -> VGPR<=64, 2 blocks/CU
void qattn_kernel(const float* __restrict__ x, const float* __restrict__ theta,
                  const float* __restrict__ wc, const float* __restrict__ bc,
                  float* __restrict__ out)
{
    __shared__ float ldsq[HALF * NWIRES];   // 65536 B; re-used for partials+scramble
    float* part = ldsq;                      // [TPB][9] = 36864 B (after main loop)
    float* attn = ldsq + TPB * 9;            // [ROWS][8] = 4096 B

    const int tid = threadIdx.x;
    const int r   = tid & (ROWS - 1);        // local s-row
    const int g   = tid >> 7;                // t-group (wave-uniform)
    const int b   = blockIdx.x >> 5;         // 32 s-chunks per batch
    const int S0  = (blockIdx.x & 31) * ROWS;

    float th[8];
#pragma unroll
    for (int w = 0; w < 8; ++w) th[w] = theta[w];

    const float* xb = x + ((size_t)b * SEQ) * NWIRES;

    // ---- own row q_s, pre-scaled by log2(e)/sqrt(2) so p = exp2(dot) ----
    const int s = S0 + r;
    v2f q01, q23, q45, q67;
    {
        const float4 xa  = *(const float4*)(xb + s * 8);
        const float4 xb4 = *(const float4*)(xb + s * 8 + 4);
        float c0 = __cosf(xa.x  + th[0]);
        float c1 = __cosf(xa.y  + th[1]);
        float c2 = __cosf(xa.z  + th[2]);
        float c3 = __cosf(xa.w  + th[3]);
        float c4 = __cosf(xb4.x + th[4]);
        float c5 = __cosf(xb4.y + th[5]);
        float c6 = __cosf(xb4.z + th[6]);
        float c7 = __cosf(xb4.w + th[7]);
        float q1 = c0 * c1;
        float q2 = q1 * c2;
        float q3 = q2 * c3;
        float q4 = q3 * c4;
        float q5 = q4 * c5;
        float q6 = q5 * c6;
        float q7 = q6 * c7;
        float q0 = c1 * c2 * c3 * c4 * c5 * c6 * c7;
        const float sc = 0.70710678118654752f * 1.44269504088896341f;
        q01 = (v2f){q0 * sc, q1 * sc};
        q23 = (v2f){q2 * sc, q3 * sc};
        q45 = (v2f){q4 * sc, q5 * sc};
        q67 = (v2f){q6 * sc, q7 * sc};
    }

    v2f a01 = {0.f, 0.f}, a23 = {0.f, 0.f}, a45 = {0.f, 0.f}, a67 = {0.f, 0.f};
    float ssum = 0.f;

    for (int half = 0; half < 2; ++half) {
        __syncthreads();   // protect LDS from previous phase's readers
        const int T0 = half * HALF;
        // stage q rows [T0, T0+HALF): 1024 threads x 2 rows
#pragma unroll
        for (int k = 0; k < HALF / TPB; ++k) {
            const int tt = tid + k * TPB;
            const int t  = T0 + tt;
            const float4 xa  = *(const float4*)(xb + t * 8);
            const float4 xb4 = *(const float4*)(xb + t * 8 + 4);
            float c0 = __cosf(xa.x  + th[0]);
            float c1 = __cosf(xa.y  + th[1]);
            float c2 = __cosf(xa.z  + th[2]);
            float c3 = __cosf(xa.w  + th[3]);
            float c4 = __cosf(xb4.x + th[4]);
            float c5 = __cosf(xb4.y + th[5]);
            float c6 = __cosf(xb4.z + th[6]);
            float c7 = __cosf(xb4.w + th[7]);
            float q1 = c0 * c1;
            float q2 = q1 * c2;
            float q3 = q2 * c3;
            float q4 = q3 * c4;
            float q5 = q4 * c5;
            float q6 = q5 * c6;
            float q7 = q6 * c7;
            float q0 = c1 * c2 * c3 * c4 * c5 * c6 * c7;
            float4* dst = (float4*)(ldsq + tt * 8);
            dst[0] = make_float4(q0, q1, q2, q3);
            dst[1] = make_float4(q4, q5, q6, q7);
        }
        __syncthreads();
        // group g consumes staged rows [g*TQ, (g+1)*TQ): wave-uniform broadcast
        const float* base = ldsq + g * TQ * 8;
#pragma unroll 4
        for (int tt = 0; tt < TQ; ++tt) {
            const float4 qa = *(const float4*)(base + tt * 8);
            const float4 qb = *(const float4*)(base + tt * 8 + 4);
            v2f t0 = {qa.x, qa.y}, t1 = {qa.z, qa.w};
            v2f t2 = {qb.x, qb.y}, t3 = {qb.z, qb.w};
            v2f d = pk_mul(q01, t0);
            d = pk_fma(q23, t1, d);
            d = pk_fma(q45, t2, d);
            d = pk_fma(q67, t3, d);
            float p = EXP2F(d.x + d.y);
            ssum += p;
            v2f pv = {p, p};
            a01 = pk_fma(pv, t0, a01);
            a23 = pk_fma(pv, t1, a23);
            a45 = pk_fma(pv, t2, a45);
            a67 = pk_fma(pv, t3, a67);
        }
    }

    // ---- combine the 8 t-group partials through LDS ----
    __syncthreads();                       // main-loop readers done; reuse LDS
    {
        float* p9 = part + tid * 9;        // stride 9: coprime with 32 banks
        p9[0] = a01.x; p9[1] = a01.y; p9[2] = a23.x; p9[3] = a23.y;
        p9[4] = a45.x; p9[5] = a45.y; p9[6] = a67.x; p9[7] = a67.y;
        p9[8] = ssum;
    }
    __syncthreads();
    if (tid < ROWS) {
        float acc[8] = {0, 0, 0, 0, 0, 0, 0, 0};
        float sm = 0.f;
#pragma unroll
        for (int gg = 0; gg < GRP; ++gg) {
            const float* p9 = part + (gg * ROWS + tid) * 9;
#pragma unroll
            for (int j = 0; j < 8; ++j) acc[j] += p9[j];
            sm += p9[8];
        }
        const float inv = 1.0f / sm;
#pragma unroll
        for (int j = 0; j < 8; ++j) attn[tid * 8 + j] = acc[j] * inv;
    }
    __syncthreads();

    // ---- epilogue: resolve swapaxes/reshape scramble ----
    if (tid < ROWS) {
        const int e = tid >> 4;            // 8 wires
        const int i = tid & 15;            // 16 output rows per wire in this chunk
        const int rr = e * 512 + (S0 >> 3) + i;
        float y[8];
#pragma unroll
        for (int c = 0; c < 8; ++c) y[c] = attn[(i * 8 + c) * 8 + e];
        float o[8];
#pragma unroll
        for (int k = 0; k < 8; ++k) {
            float a = bc[k];
#pragma unroll
            for (int c = 0; c < 8; ++c) a += y[c] * wc[k * 8 + c];
            o[k] = a;
        }
        float4* op = (float4*)(out + ((size_t)b * SEQ + rr) * 8);
        op[0] = make_float4(o[0], o[1], o[2], o[3]);
        op[1] = make_float4(o[4], o[5], o[6], o[7]);
    }
}

extern "C" void kernel_launch(void* const* d_in, const int* in_sizes, int n_in,
                              void* d_out, int out_size, void* d_ws, size_t ws_size,
                              hipStream_t stream)
{
    const float* x  = (const float*)d_in[0];
    const float* th = (const float*)d_in[1];
    const float* wc = (const float*)d_in[2];
    const float* bc = (const float*)d_in[3];
    float* out = (float*)d_out;

    qattn_kernel<<<dim3(NBATCH * (SEQ / ROWS)), dim3(TPB), 0, stream>>>(x, th, wc, bc, out);
}

// Round 5
// 166.303 us; speedup vs baseline: 1.4989x; 1.0403x over previous
//
#include <hip/hip_runtime.h>
#include <math.h>

// Closed form derived from the reference:
//   q[n,0] = prod_{v=1..7} cos(x[n,v]+theta[v])
//   q[n,w] = prod_{v=0..w} cos(x[n,v]+theta[v])   (w = 1..7)
// Attention with E=8, no-max softmax (|score| <= 8/sqrt2), output scramble:
//   final[b,r,k] = sum_c att[b,(r%512)*8+c, r/512] * W[k,c] + bias[k].
//
// R4: LDS pipe was the wall (2 ds_read_b128/iter x 16K wave-iters/CU x ~10cyc
//     = 134us, exactly measured). Fix: 4 s-rows per thread -> LDS reads /4,
//     VALU becomes binding at ~48us. ROWS=256, 64 lane-slots x RPT=4, GRP=16
//     wave-uniform t-groups, grid=256 (1 block/CU).

#define NWIRES 8
#define SEQ    4096
#define NBATCH 16
#define ROWS   256    // s-rows per block
#define RPT    4      // s-rows per thread
#define SLOTS  64     // ROWS/RPT = lanes per group
#define GRP    16     // t-split groups (= waves per block)
#define TPB    1024   // GRP * SLOTS
#define HALF   2048   // q rows staged in LDS per phase (64 KB)
#define TQ     (HALF / GRP)   // 128 t-iters per thread per phase

typedef float v2f __attribute__((ext_vector_type(2)));

static __device__ __forceinline__ v2f pk_mul(v2f a, v2f b) {
    v2f d; asm("v_pk_mul_f32 %0, %1, %2" : "=v"(d) : "v"(a), "v"(b)); return d;
}
static __device__ __forceinline__ v2f pk_fma(v2f a, v2f b, v2f c) {
    v2f d; asm("v_pk_fma_f32 %0, %1, %2, %3" : "=v"(d) : "v"(a), "v"(b), "v"(c)); return d;
}

#if __has_builtin(__builtin_amdgcn_exp2f)
#define EXP2F(x) __builtin_amdgcn_exp2f(x)
#else
#define EXP2F(x) __expf((x) * 0.69314718055994531f)
#endif

__global__ __launch_bounds__(TPB, 4)   // cap 128 VGPR; 16 waves/CU, 1 block/CU
void qattn_kernel(const float* __restrict__ x, const float* __restrict__ theta,
                  const float* __restrict__ wc, const float* __restrict__ bc,
                  float* __restrict__ out)
{
    __shared__ float ldsq[HALF * NWIRES];   // 65536 B; re-used for combine
    float* part = ldsq;                      // [TPB][9]  = 36864 B
    float* red  = ldsq + TPB * 9;            // [SLOTS][9] = 2304 B
    float* attn = red + SLOTS * 9;           // [ROWS][8] = 8192 B

    const int tid = threadIdx.x;
    const int r   = tid & (SLOTS - 1);       // lane slot (0..63)
    const int g   = tid >> 6;                // t-group == wave id (wave-uniform)
    const int b   = blockIdx.x >> 4;         // 16 s-chunks per batch
    const int S0  = (blockIdx.x & 15) * ROWS;

    float th[8];
#pragma unroll
    for (int w = 0; w < 8; ++w) th[w] = theta[w];

    const float* xb = x + ((size_t)b * SEQ) * NWIRES;

    // ---- own rows q_s (RPT of them), pre-scaled by log2(e)/sqrt(2) ----
    v2f q0[RPT], q1[RPT], q2[RPT], q3[RPT];
#pragma unroll
    for (int j = 0; j < RPT; ++j) {
        const int s = S0 + j * SLOTS + r;
        const float4 xa  = *(const float4*)(xb + s * 8);
        const float4 xb4 = *(const float4*)(xb + s * 8 + 4);
        float c0 = __cosf(xa.x  + th[0]);
        float c1 = __cosf(xa.y  + th[1]);
        float c2 = __cosf(xa.z  + th[2]);
        float c3 = __cosf(xa.w  + th[3]);
        float c4 = __cosf(xb4.x + th[4]);
        float c5 = __cosf(xb4.y + th[5]);
        float c6 = __cosf(xb4.z + th[6]);
        float c7 = __cosf(xb4.w + th[7]);
        float p1 = c0 * c1;
        float p2 = p1 * c2;
        float p3 = p2 * c3;
        float p4 = p3 * c4;
        float p5 = p4 * c5;
        float p6 = p5 * c6;
        float p7 = p6 * c7;
        float p0 = c1 * c2 * c3 * c4 * c5 * c6 * c7;
        const float sc = 0.70710678118654752f * 1.44269504088896341f;
        q0[j] = (v2f){p0 * sc, p1 * sc};
        q1[j] = (v2f){p2 * sc, p3 * sc};
        q2[j] = (v2f){p4 * sc, p5 * sc};
        q3[j] = (v2f){p6 * sc, p7 * sc};
    }

    v2f a0[RPT], a1[RPT], a2[RPT], a3[RPT];
    float ssum[RPT];
#pragma unroll
    for (int j = 0; j < RPT; ++j) {
        a0[j] = (v2f){0.f, 0.f}; a1[j] = (v2f){0.f, 0.f};
        a2[j] = (v2f){0.f, 0.f}; a3[j] = (v2f){0.f, 0.f};
        ssum[j] = 0.f;
    }

    for (int half = 0; half < 2; ++half) {
        __syncthreads();   // protect LDS from previous phase's readers
        const int T0 = half * HALF;
        // stage q rows [T0, T0+HALF): 1024 threads x 2 rows
#pragma unroll
        for (int k = 0; k < HALF / TPB; ++k) {
            const int tt = tid + k * TPB;
            const int t  = T0 + tt;
            const float4 xa  = *(const float4*)(xb + t * 8);
            const float4 xb4 = *(const float4*)(xb + t * 8 + 4);
            float c0 = __cosf(xa.x  + th[0]);
            float c1 = __cosf(xa.y  + th[1]);
            float c2 = __cosf(xa.z  + th[2]);
            float c3 = __cosf(xa.w  + th[3]);
            float c4 = __cosf(xb4.x + th[4]);
            float c5 = __cosf(xb4.y + th[5]);
            float c6 = __cosf(xb4.z + th[6]);
            float c7 = __cosf(xb4.w + th[7]);
            float p1 = c0 * c1;
            float p2 = p1 * c2;
            float p3 = p2 * c3;
            float p4 = p3 * c4;
            float p5 = p4 * c5;
            float p6 = p5 * c6;
            float p7 = p6 * c7;
            float p0 = c1 * c2 * c3 * c4 * c5 * c6 * c7;
            float4* dst = (float4*)(ldsq + tt * 8);
            dst[0] = make_float4(p0, p1, p2, p3);
            dst[1] = make_float4(p4, p5, p6, p7);
        }
        __syncthreads();
        // group g consumes staged rows [g*TQ, (g+1)*TQ): wave-uniform broadcast
        const float* base = ldsq + g * TQ * 8;
#pragma unroll 4
        for (int tt = 0; tt < TQ; ++tt) {
            const float4 qa = *(const float4*)(base + tt * 8);
            const float4 qb = *(const float4*)(base + tt * 8 + 4);
            v2f t0 = {qa.x, qa.y}, t1 = {qa.z, qa.w};
            v2f t2 = {qb.x, qb.y}, t3 = {qb.z, qb.w};
#pragma unroll
            for (int j = 0; j < RPT; ++j) {
                v2f d = pk_mul(q0[j], t0);
                d = pk_fma(q1[j], t1, d);
                d = pk_fma(q2[j], t2, d);
                d = pk_fma(q3[j], t3, d);
                float p = EXP2F(d.x + d.y);
                ssum[j] += p;
                v2f pv = {p, p};
                a0[j] = pk_fma(pv, t0, a0[j]);
                a1[j] = pk_fma(pv, t1, a1[j]);
                a2[j] = pk_fma(pv, t2, a2[j]);
                a3[j] = pk_fma(pv, t3, a3[j]);
            }
        }
    }

    // ---- combine the GRP t-group partials, one row-of-RPT per pass ----
#pragma unroll 1
    for (int j = 0; j < RPT; ++j) {
        __syncthreads();                  // LDS region free (readers done)
        float* p9 = part + tid * 9;       // stride 9: coprime with 32 banks
        p9[0] = a0[j].x; p9[1] = a0[j].y; p9[2] = a1[j].x; p9[3] = a1[j].y;
        p9[4] = a2[j].x; p9[5] = a2[j].y; p9[6] = a3[j].x; p9[7] = a3[j].y;
        p9[8] = ssum[j];
        __syncthreads();
        if (tid < SLOTS * 9) {            // 576 reducers: (slot rr, comp k)
            const int rr = tid / 9;
            const int k  = tid - rr * 9;
            float sm = 0.f;
#pragma unroll
            for (int gg = 0; gg < GRP; ++gg)
                sm += part[(gg * SLOTS + rr) * 9 + k];
            red[rr * 9 + k] = sm;
        }
        __syncthreads();
        if (tid < SLOTS * 8) {            // 512: (slot rr, wire w)
            const int rr = tid >> 3;
            const int w  = tid & 7;
            attn[(j * SLOTS + rr) * 8 + w] =
                red[rr * 9 + w] / red[rr * 9 + 8];
        }
    }
    __syncthreads();

    // ---- epilogue: resolve swapaxes/reshape scramble ----
    if (tid < ROWS) {
        const int e = tid >> 5;            // wire (0..7)
        const int i = tid & 31;            // 32 output rows per wire per chunk
        const int rr = e * 512 + (S0 >> 3) + i;
        float y[8];
#pragma unroll
        for (int c = 0; c < 8; ++c) y[c] = attn[(i * 8 + c) * 8 + e];
        float o[8];
#pragma unroll
        for (int k = 0; k < 8; ++k) {
            float a = bc[k];
#pragma unroll
            for (int c = 0; c < 8; ++c) a += y[c] * wc[k * 8 + c];
            o[k] = a;
        }
        float4* op = (float4*)(out + ((size_t)b * SEQ + rr) * 8);
        op[0] = make_float4(o[0], o[1], o[2], o[3]);
        op[1] = make_float4(o[4], o[5], o[6], o[7]);
    }
}

extern "C" void kernel_launch(void* const* d_in, const int* in_sizes, int n_in,
                              void* d_out, int out_size, void* d_ws, size_t ws_size,
                              hipStream_t stream)
{
    const float* x  = (const float*)d_in[0];
    const float* th = (const float*)d_in[1];
    const float* wc = (const float*)d_in[2];
    const float* bc = (const float*)d_in[3];
    float* out = (float*)d_out;

    qattn_kernel<<<dim3(NBATCH * (SEQ / ROWS)), dim3(TPB), 0, stream>>>(x, th, wc, bc, out);
}

// Round 6
// 114.056 us; speedup vs baseline: 2.1855x; 1.4581x over previous
//
#include <hip/hip_runtime.h>
#include <math.h>

// Closed form derived from the reference:
//   q[n,0] = prod_{v=1..7} cos(x[n,v]+theta[v])
//   q[n,w] = prod_{v=0..w} cos(x[n,v]+theta[v])   (w = 1..7)
// Attention with E=8, no-max softmax (|score| <= 8/sqrt2), output scramble:
//   final[b,r,k] = sum_c att[b,(r%512)*8+c, r/512] * W[k,c] + bias[k].
//
// R5: MFMA flash. v_pk_fma_f32 is half-rate on CDNA4 (fp32 spec 157TF = scalar
//     rate) so the scalar-VALU path plateaus ~128us. Rewrite on the idle matrix
//     pipe: v_mfma_f32_16x16x16_f16, scores computed TRANSPOSED (A=K, B=Q) so
//     the C/D fragment (St[t=4h+reg][s=lane&15]) is bit-identical to the PV
//     A-fragment (P[s=lane&15][t=4h+j]) -> exp2+cvt only, no cross-lane moves.
//     Denominator = ones column (w=8) in V. 4 waves/block x 16 q-rows,
//     t staged in 512-chunks: kf[t][16] row-major (K-frags) + vt[16][520]
//     transposed/padded (V-frags).

#define SEQ   4096
#define NB    16
#define TPB   256
#define TC    512          // t rows staged per chunk
#define NTILE (TC / 16)    // 32 tiles per chunk
#define VSTR  520          // vt row stride in f16 (pad 8 kills bank conflicts)

typedef _Float16 f16x4 __attribute__((ext_vector_type(4)));
typedef float    f32x4 __attribute__((ext_vector_type(4)));

#if __has_builtin(__builtin_amdgcn_exp2f)
#define EXP2F(x) __builtin_amdgcn_exp2f(x)
#else
#define EXP2F(x) exp2f(x)
#endif

__global__ __launch_bounds__(TPB, 4)   // 4 blocks/CU (33 KB LDS each), VGPR<=128
void qattn_kernel(const float* __restrict__ x, const float* __restrict__ theta,
                  const float* __restrict__ wc, const float* __restrict__ bc,
                  float* __restrict__ out)
{
    __shared__ _Float16 kf[TC * 16];     // [t][16]: w 0..7 real, 8..15 zero (16 KB)
    __shared__ _Float16 vt[16 * VSTR];   // [w][t]: w<8 = q, w=8 = ones, w>8 = 0

    const int tid  = threadIdx.x;
    const int lane = tid & 63;
    const int wv   = tid >> 6;           // wave id 0..3
    const int h    = lane >> 4;          // quad-group 0..3
    const int tl   = lane & 15;

    const int b  = blockIdx.x >> 6;      // batch
    const int S0 = (blockIdx.x & 63) * 64;
    const float* xb = x + (size_t)b * SEQ * 8;

    float th[8];
#pragma unroll
    for (int w = 0; w < 8; ++w) th[w] = theta[w];

    // vt rows 8..15: denominator ones row (w=8), zeros above. Written once;
    // chunk staging only touches rows 0..7, so this persists across chunks.
    for (int idx = tid; idx < 8 * VSTR; idx += TPB) {
        vt[8 * VSTR + idx] = (idx < VSTR) ? (_Float16)1.0f : (_Float16)0.0f;
    }

    // ---- per-lane Q fragment (B operand): B[k=w=4h+j][n=s=tl] ----
    // scale log2(e)/sqrt(2) folded here so softmax is exp2(c) directly.
    f16x4 qfrag = {(_Float16)0.f, (_Float16)0.f, (_Float16)0.f, (_Float16)0.f};
    {
        const int s = S0 + wv * 16 + tl;
        const float4 xa  = *(const float4*)(xb + s * 8);
        const float4 xb4 = *(const float4*)(xb + s * 8 + 4);
        float c0 = __cosf(xa.x  + th[0]);
        float c1 = __cosf(xa.y  + th[1]);
        float c2 = __cosf(xa.z  + th[2]);
        float c3 = __cosf(xa.w  + th[3]);
        float c4 = __cosf(xb4.x + th[4]);
        float c5 = __cosf(xb4.y + th[5]);
        float c6 = __cosf(xb4.z + th[6]);
        float c7 = __cosf(xb4.w + th[7]);
        float p1 = c0 * c1, p2 = p1 * c2, p3 = p2 * c3, p4 = p3 * c4;
        float p5 = p4 * c5, p6 = p5 * c6, p7 = p6 * c7;
        float p0 = c1 * c2 * c3 * c4 * c5 * c6 * c7;
        const float sc = 0.70710678118654752f * 1.44269504088896341f;
        if (h == 0)
            qfrag = (f16x4){(_Float16)(p0*sc), (_Float16)(p1*sc),
                            (_Float16)(p2*sc), (_Float16)(p3*sc)};
        else if (h == 1)
            qfrag = (f16x4){(_Float16)(p4*sc), (_Float16)(p5*sc),
                            (_Float16)(p6*sc), (_Float16)(p7*sc)};
    }

    f32x4 o = {0.f, 0.f, 0.f, 0.f};      // O[s=4h+reg][w=tl]; tl==8 -> sum(p)

    for (int ch = 0; ch < SEQ / TC; ++ch) {
        __syncthreads();                  // previous chunk's readers done
        // ---- stage chunk: 512 t-rows, 2 per thread ----
#pragma unroll
        for (int rr = 0; rr < TC / TPB; ++rr) {
            const int tt = rr * TPB + tid;
            const int t  = ch * TC + tt;
            const float4 xa  = *(const float4*)(xb + t * 8);
            const float4 xb4 = *(const float4*)(xb + t * 8 + 4);
            float c0 = __cosf(xa.x  + th[0]);
            float c1 = __cosf(xa.y  + th[1]);
            float c2 = __cosf(xa.z  + th[2]);
            float c3 = __cosf(xa.w  + th[3]);
            float c4 = __cosf(xb4.x + th[4]);
            float c5 = __cosf(xb4.y + th[5]);
            float c6 = __cosf(xb4.z + th[6]);
            float c7 = __cosf(xb4.w + th[7]);
            float p1 = c0 * c1, p2 = p1 * c2, p3 = p2 * c3, p4 = p3 * c4;
            float p5 = p4 * c5, p6 = p5 * c6, p7 = p6 * c7;
            float p0 = c1 * c2 * c3 * c4 * c5 * c6 * c7;
            _Float16 h0 = (_Float16)p0, h1 = (_Float16)p1, h2 = (_Float16)p2,
                     h3 = (_Float16)p3, h4 = (_Float16)p4, h5 = (_Float16)p5,
                     h6 = (_Float16)p6, h7 = (_Float16)p7;
            _Float16* krow = kf + tt * 16;
            *(f16x4*)(krow)      = (f16x4){h0, h1, h2, h3};
            *(f16x4*)(krow + 4)  = (f16x4){h4, h5, h6, h7};
            *(f16x4*)(krow + 8)  = (f16x4){(_Float16)0.f, (_Float16)0.f,
                                           (_Float16)0.f, (_Float16)0.f};
            *(f16x4*)(krow + 12) = (f16x4){(_Float16)0.f, (_Float16)0.f,
                                           (_Float16)0.f, (_Float16)0.f};
            vt[0 * VSTR + tt] = h0; vt[1 * VSTR + tt] = h1;
            vt[2 * VSTR + tt] = h2; vt[3 * VSTR + tt] = h3;
            vt[4 * VSTR + tt] = h4; vt[5 * VSTR + tt] = h5;
            vt[6 * VSTR + tt] = h6; vt[7 * VSTR + tt] = h7;
        }
        __syncthreads();
        // ---- per wave: 32 score tiles (16s x 16t each) ----
        const _Float16* kbase = kf + tl * 16 + h * 4;   // A: K[t=tl][w=4h+j]
        const _Float16* vbase = vt + tl * VSTR + h * 4; // B: V[t=4h+j][w=tl]
#pragma unroll 4
        for (int i = 0; i < NTILE; ++i) {
            f16x4 kfrag = *(const f16x4*)(kbase + i * 256);
            f32x4 c = __builtin_amdgcn_mfma_f32_16x16x16f16(
                kfrag, qfrag, (f32x4){0.f, 0.f, 0.f, 0.f}, 0, 0, 0);
            // St[t=4h+reg][s=tl] -> P A-frag is the SAME (lane,idx) mapping
            f16x4 pf = {(_Float16)EXP2F(c.x), (_Float16)EXP2F(c.y),
                        (_Float16)EXP2F(c.z), (_Float16)EXP2F(c.w)};
            f16x4 vfrag = *(const f16x4*)(vbase + i * 16);
            o = __builtin_amdgcn_mfma_f32_16x16x16f16(pf, vfrag, o, 0, 0, 0);
        }
    }

    // ---- normalize: denominators live in lanes tl==8 (same h, same reg) ----
    const int src = (lane & 48) | 8;
    const float d0 = __shfl(o.x, src);
    const float d1 = __shfl(o.y, src);
    const float d2 = __shfl(o.z, src);
    const float d3 = __shfl(o.w, src);

    __syncthreads();                      // done reading kf; reuse as attn
    float* attn = (float*)kf;             // [64][8]
    if (tl < 8) {
        const int sb = wv * 16 + 4 * h;
        attn[(sb + 0) * 8 + tl] = o.x / d0;
        attn[(sb + 1) * 8 + tl] = o.y / d1;
        attn[(sb + 2) * 8 + tl] = o.z / d2;
        attn[(sb + 3) * 8 + tl] = o.w / d3;
    }
    __syncthreads();

    // ---- epilogue: resolve swapaxes/reshape scramble + combine ----
    if (tid < 64) {
        const int e = tid >> 3;           // wire
        const int i = tid & 7;
        const int r = e * 512 + (S0 >> 3) + i;
        float y[8];
#pragma unroll
        for (int c2 = 0; c2 < 8; ++c2) y[c2] = attn[(i * 8 + c2) * 8 + e];
        float oo[8];
#pragma unroll
        for (int k = 0; k < 8; ++k) {
            float a = bc[k];
#pragma unroll
            for (int c2 = 0; c2 < 8; ++c2) a += y[c2] * wc[k * 8 + c2];
            oo[k] = a;
        }
        float4* op = (float4*)(out + ((size_t)b * SEQ + r) * 8);
        op[0] = make_float4(oo[0], oo[1], oo[2], oo[3]);
        op[1] = make_float4(oo[4], oo[5], oo[6], oo[7]);
    }
}

extern "C" void kernel_launch(void* const* d_in, const int* in_sizes, int n_in,
                              void* d_out, int out_size, void* d_ws, size_t ws_size,
                              hipStream_t stream)
{
    const float* x  = (const float*)d_in[0];
    const float* th = (const float*)d_in[1];
    const float* wc = (const float*)d_in[2];
    const float* bc = (const float*)d_in[3];
    float* out = (float*)d_out;

    qattn_kernel<<<dim3(NB * (SEQ / 64)), dim3(TPB), 0, stream>>>(x, th, wc, bc, out);
}

// Round 7
// 109.003 us; speedup vs baseline: 2.2868x; 1.0464x over previous
//
#include <hip/hip_runtime.h>
#include <math.h>

// Closed form derived from the reference:
//   q[n,0] = prod_{v=1..7} cos(x[n,v]+theta[v])
//   q[n,w] = prod_{v=0..w} cos(x[n,v]+theta[v])   (w = 1..7)
// Attention with E=8, no-max softmax (|score| <= 8/sqrt2), output scramble:
//   final[b,r,k] = sum_c att[b,(r%512)*8+c, r/512] * W[k,c] + bias[k].
//
// R6: 32x32x8 MFMA (K=8 == wire count, no zero-padding waste). Scores computed
//     transposed: C(32x32) regs [4u..4u+3] ARE the PV A-frag for t-slice u
//     (k=4(lane>>5)+j -> t=8u+4(lane>>5)+j) -> exp2+pack only, no cross-lane.
//     Denominator = ones row w=8 in V. Conflict-free LDS: kf stride 12 f16
//     (6 words, 2-way=free), vt XOR-swizzled (word = w*256 + ((t/2)^2w)).
//     4 waves x 32 s-rows = 128 s/block, grid 512 (2 blocks/CU).

#define SEQ   4096
#define NB    16
#define TPB   256
#define SROWS 128
#define TC    512          // t rows staged per chunk
#define NTILE (TC / 32)    // 16 t-tiles per chunk
#define KSTR  12           // kf row stride in f16 (24 B = 6 words)

typedef _Float16 f16x2  __attribute__((ext_vector_type(2)));
typedef _Float16 f16x4  __attribute__((ext_vector_type(4)));
typedef float    f32x16 __attribute__((ext_vector_type(16)));

#if __has_builtin(__builtin_amdgcn_exp2f)
#define EXP2F(x) __builtin_amdgcn_exp2f(x)
#else
#define EXP2F(x) exp2f(x)
#endif

#if __has_builtin(__builtin_amdgcn_cvt_pkrtz)
#define PKRTZ(a, b) __builtin_amdgcn_cvt_pkrtz((a), (b))
#else
static __device__ __forceinline__ f16x2 PKRTZ(float a, float b) {
    return (f16x2){(_Float16)a, (_Float16)b};
}
#endif

__global__ __launch_bounds__(TPB, 4)   // VGPR cap 128
void qattn_kernel(const float* __restrict__ x, const float* __restrict__ theta,
                  const float* __restrict__ wc, const float* __restrict__ bc,
                  float* __restrict__ out)
{
    __shared__ __align__(16) _Float16 kf[TC * KSTR];  // K: [t][8 f16 + 4 pad] = 12 KB
    __shared__ __align__(16) _Float16 vt[10 * 512];   // V^T swizzled: 10 rows x 256 words

    const int tid  = threadIdx.x;
    const int lane = tid & 63;
    const int wv   = tid >> 6;           // wave 0..3 -> s-rows [wv*32, wv*32+32)
    const int l31  = lane & 31;
    const int hp   = lane >> 5;          // half-wave

    const int b  = blockIdx.x >> 5;      // batch
    const int S0 = (blockIdx.x & 31) * SROWS;
    const float* xb = x + (size_t)b * SEQ * 8;

    float th[8];
#pragma unroll
    for (int w = 0; w < 8; ++w) th[w] = theta[w];

    // ---- Q fragment (B operand of QK): B[k=w=4hp+j][n=s=l31], scaled ----
    f16x4 qfrag;
    {
        const int s = S0 + wv * 32 + l31;
        const float4 xa  = *(const float4*)(xb + s * 8);
        const float4 xb4 = *(const float4*)(xb + s * 8 + 4);
        float c0 = __cosf(xa.x  + th[0]);
        float c1 = __cosf(xa.y  + th[1]);
        float c2 = __cosf(xa.z  + th[2]);
        float c3 = __cosf(xa.w  + th[3]);
        float c4 = __cosf(xb4.x + th[4]);
        float c5 = __cosf(xb4.y + th[5]);
        float c6 = __cosf(xb4.z + th[6]);
        float c7 = __cosf(xb4.w + th[7]);
        float p1 = c0 * c1, p2 = p1 * c2, p3 = p2 * c3, p4 = p3 * c4;
        float p5 = p4 * c5, p6 = p5 * c6, p7 = p6 * c7;
        float p0 = c1 * c2 * c3 * c4 * c5 * c6 * c7;
        const float sc = 0.70710678118654752f * 1.44269504088896341f;
        if (hp == 0)
            qfrag = (f16x4){(_Float16)(p0*sc), (_Float16)(p1*sc),
                            (_Float16)(p2*sc), (_Float16)(p3*sc)};
        else
            qfrag = (f16x4){(_Float16)(p4*sc), (_Float16)(p5*sc),
                            (_Float16)(p6*sc), (_Float16)(p7*sc)};
    }

    f32x16 o = {0.f,0.f,0.f,0.f,0.f,0.f,0.f,0.f,0.f,0.f,0.f,0.f,0.f,0.f,0.f,0.f};

    const int wr = (l31 < 9) ? l31 : 9;   // lanes w>8: harmless garbage column
    const int vx = 2 * wr;                // XOR swizzle key
    const _Float16* kfb = kf + l31 * KSTR + 4 * hp;

    for (int ch = 0; ch < SEQ / TC; ++ch) {
        __syncthreads();                  // previous chunk's readers done
        // ---- stage 512 t-rows (2 per thread) into kf + swizzled vt ----
#pragma unroll
        for (int rr = 0; rr < TC / TPB; ++rr) {
            const int tt = rr * TPB + tid;
            const int t  = ch * TC + tt;
            const float4 xa  = *(const float4*)(xb + t * 8);
            const float4 xb4 = *(const float4*)(xb + t * 8 + 4);
            float c0 = __cosf(xa.x  + th[0]);
            float c1 = __cosf(xa.y  + th[1]);
            float c2 = __cosf(xa.z  + th[2]);
            float c3 = __cosf(xa.w  + th[3]);
            float c4 = __cosf(xb4.x + th[4]);
            float c5 = __cosf(xb4.y + th[5]);
            float c6 = __cosf(xb4.z + th[6]);
            float c7 = __cosf(xb4.w + th[7]);
            float p1 = c0 * c1, p2 = p1 * c2, p3 = p2 * c3, p4 = p3 * c4;
            float p5 = p4 * c5, p6 = p5 * c6, p7 = p6 * c7;
            float p0 = c1 * c2 * c3 * c4 * c5 * c6 * c7;
            _Float16 h0 = (_Float16)p0, h1 = (_Float16)p1, h2 = (_Float16)p2,
                     h3 = (_Float16)p3, h4 = (_Float16)p4, h5 = (_Float16)p5,
                     h6 = (_Float16)p6, h7 = (_Float16)p7;
            _Float16* krow = kf + tt * KSTR;
            *(f16x4*)(krow)     = (f16x4){h0, h1, h2, h3};
            *(f16x4*)(krow + 4) = (f16x4){h4, h5, h6, h7};
            const int c  = tt >> 1;       // logical word (pair of t)
            const int hb = tt & 1;        // halfword within word
            vt[2*(0*256 + (c ^  0)) + hb] = h0;
            vt[2*(1*256 + (c ^  2)) + hb] = h1;
            vt[2*(2*256 + (c ^  4)) + hb] = h2;
            vt[2*(3*256 + (c ^  6)) + hb] = h3;
            vt[2*(4*256 + (c ^  8)) + hb] = h4;
            vt[2*(5*256 + (c ^ 10)) + hb] = h5;
            vt[2*(6*256 + (c ^ 12)) + hb] = h6;
            vt[2*(7*256 + (c ^ 14)) + hb] = h7;
            vt[2*(8*256 + (c ^ 16)) + hb] = (_Float16)1.0f;  // denominator row
        }
        __syncthreads();
        // ---- 16 t-tiles: 1 QK MFMA -> exp2 -> 4 PV MFMAs (layout identity) ----
#pragma unroll 2
        for (int i = 0; i < NTILE; ++i) {
            f16x4 kfrag = *(const f16x4*)(kfb + i * 32 * KSTR);
            f32x16 cc = __builtin_amdgcn_mfma_f32_32x32x8f16(
                kfrag, qfrag, (f32x16){0.f,0.f,0.f,0.f,0.f,0.f,0.f,0.f,
                                       0.f,0.f,0.f,0.f,0.f,0.f,0.f,0.f}, 0, 0, 0);
#pragma unroll
            for (int u = 0; u < 4; ++u) {
                auto lo = PKRTZ(EXP2F(cc[4*u+0]), EXP2F(cc[4*u+1]));
                auto hi = PKRTZ(EXP2F(cc[4*u+2]), EXP2F(cc[4*u+3]));
                f16x4 pf;
                pf.x = lo.x; pf.y = lo.y; pf.z = hi.x; pf.w = hi.y;
                const int cw   = 16*i + 4*u + 2*hp;           // logical word
                const int phys = wr * 256 + (cw ^ vx);        // swizzled
                f16x4 vfrag = *(const f16x4*)(vt + 2 * phys);
                o = __builtin_amdgcn_mfma_f32_32x32x8f16(pf, vfrag, o, 0, 0, 0);
            }
        }
    }

    // ---- normalize: denominators in lanes col==8 (same half-wave) ----
    float dd[16];
    const int src = (lane & 32) | 8;
#pragma unroll
    for (int r = 0; r < 16; ++r) dd[r] = __shfl(o[r], src, 64);

    __syncthreads();                      // done with kf; reuse as attn
    float* attn = (float*)kf;             // [SROWS][9] f32 = 4608 B
    if (l31 < 8) {
#pragma unroll
        for (int r = 0; r < 16; ++r) {
            const int sloc = wv * 32 + (r & 3) + 8 * (r >> 2) + 4 * hp;
            attn[sloc * 9 + l31] = o[r] / dd[r];
        }
    }
    __syncthreads();

    // ---- epilogue: swapaxes/reshape scramble + 8x8 combine ----
    if (tid < 128) {
        const int e    = tid >> 4;        // wire
        const int nloc = tid & 15;        // local n (s-group of 8)
        const int r    = e * 512 + (S0 >> 3) + nloc;
        float y[8];
#pragma unroll
        for (int c = 0; c < 8; ++c) y[c] = attn[(nloc * 8 + c) * 9 + e];
        float oo[8];
#pragma unroll
        for (int k = 0; k < 8; ++k) {
            float a = bc[k];
#pragma unroll
            for (int c = 0; c < 8; ++c) a += y[c] * wc[k * 8 + c];
            oo[k] = a;
        }
        float4* op = (float4*)(out + ((size_t)b * SEQ + r) * 8);
        op[0] = make_float4(oo[0], oo[1], oo[2], oo[3]);
        op[1] = make_float4(oo[4], oo[5], oo[6], oo[7]);
    }
}

extern "C" void kernel_launch(void* const* d_in, const int* in_sizes, int n_in,
                              void* d_out, int out_size, void* d_ws, size_t ws_size,
                              hipStream_t stream)
{
    const float* x  = (const float*)d_in[0];
    const float* th = (const float*)d_in[1];
    const float* wc = (const float*)d_in[2];
    const float* bc = (const float*)d_in[3];
    float* out = (float*)d_out;

    qattn_kernel<<<dim3(NB * (SEQ / SROWS)), dim3(TPB), 0, stream>>>(x, th, wc, bc, out);
}

// Round 10
// 96.405 us; speedup vs baseline: 2.5856x; 1.1307x over previous
//
#include <hip/hip_runtime.h>
#include <math.h>

// Closed form derived from the reference:
//   q[n,0] = prod_{v=1..7} cos(x[n,v]+theta[v])
//   q[n,w] = prod_{v=0..w} cos(x[n,v]+theta[v])   (w = 1..7)
// Attention with E=8, no-max softmax (|score| <= 8/sqrt2), output scramble:
//   final[b,r,k] = sum_c att[b,(r%512)*8+c, r/512] * W[k,c] + bias[k].
//
// R9: R8 with the reduce bug fixed — SROWS*9 = 1152 > TPB = 1024, so the
//     t-group reduction must be a strided loop, not `if (tid < 1152)`.
//     (R8 left attn rows 113..127 unwritten -> garbage.) Structure: TPB=1024 =
//     4 s-subtiles x 4 t-groups, 16 waves/block, 2 blocks/CU -> 32 waves/CU.
//     32x32x8 MFMA layout identity: QK^T C-regs [4u..4u+3] ARE the PV A-frag
//     for t-slice u -> exp2 + pkrtz only, zero cross-lane moves.

#define SEQ   4096
#define NB    16
#define SROWS 128          // s-rows per block (4 subtiles x 32)
#define TPB   1024
#define NTG   4            // t-groups
#define TC    1024         // t rows staged per chunk
#define TILES_PER_TG 8     // (TC/32)/NTG
#define KSTR  12           // kf row stride in f16 (24 B)

typedef _Float16 f16x4  __attribute__((ext_vector_type(4)));
typedef float    f32x16 __attribute__((ext_vector_type(16)));

#if __has_builtin(__builtin_amdgcn_exp2f)
#define EXP2F(x) __builtin_amdgcn_exp2f(x)
#else
#define EXP2F(x) exp2f(x)
#endif

__global__ __launch_bounds__(TPB, 8)   // VGPR cap 64; 2 blocks/CU -> 32 waves/CU
void qattn_kernel(const float* __restrict__ x, const float* __restrict__ theta,
                  const float* __restrict__ wc, const float* __restrict__ bc,
                  float* __restrict__ out)
{
    __shared__ __align__(16) _Float16 kf[TC * KSTR];  // 24576 B: [t][8 f16 + 4 pad]
    __shared__ __align__(16) _Float16 vt[10 * TC];    // 20480 B: V^T swizzled, 512 w/row
    // after the last MFMA barrier these are re-used:
    float* part = (float*)kf;            // [NTG][SROWS][9] = 18432 B
    float* attn = (float*)vt;            // [SROWS][9]      =  4608 B

    const int tid  = threadIdx.x;
    const int lane = tid & 63;
    const int wv   = tid >> 6;           // 0..15
    const int sub  = wv & 3;             // s-subtile (32 rows)
    const int tg   = wv >> 2;            // t-group
    const int l31  = lane & 31;
    const int hp   = lane >> 5;

    const int b  = blockIdx.x >> 5;
    const int S0 = (blockIdx.x & 31) * SROWS;
    const float* xb = x + (size_t)b * SEQ * 8;

    float th[8];
#pragma unroll
    for (int w = 0; w < 8; ++w) th[w] = theta[w];

    // ---- Q fragment (B operand of QK): B[k=w=4hp+j][n=s=l31], scaled ----
    f16x4 qfrag;
    {
        const int s = S0 + sub * 32 + l31;
        const float4 xa  = *(const float4*)(xb + s * 8);
        const float4 xb4 = *(const float4*)(xb + s * 8 + 4);
        float c0 = __cosf(xa.x  + th[0]);
        float c1 = __cosf(xa.y  + th[1]);
        float c2 = __cosf(xa.z  + th[2]);
        float c3 = __cosf(xa.w  + th[3]);
        float c4 = __cosf(xb4.x + th[4]);
        float c5 = __cosf(xb4.y + th[5]);
        float c6 = __cosf(xb4.z + th[6]);
        float c7 = __cosf(xb4.w + th[7]);
        float p1 = c0 * c1, p2 = p1 * c2, p3 = p2 * c3, p4 = p3 * c4;
        float p5 = p4 * c5, p6 = p5 * c6, p7 = p6 * c7;
        float p0 = c1 * c2 * c3 * c4 * c5 * c6 * c7;
        const float sc = 0.70710678118654752f * 1.44269504088896341f;
        if (hp == 0)
            qfrag = (f16x4){(_Float16)(p0*sc), (_Float16)(p1*sc),
                            (_Float16)(p2*sc), (_Float16)(p3*sc)};
        else
            qfrag = (f16x4){(_Float16)(p4*sc), (_Float16)(p5*sc),
                            (_Float16)(p6*sc), (_Float16)(p7*sc)};
    }

    f32x16 o = {0.f,0.f,0.f,0.f,0.f,0.f,0.f,0.f,0.f,0.f,0.f,0.f,0.f,0.f,0.f,0.f};

    const int wr = (l31 < 9) ? l31 : 9;  // lanes w>8 read row 9: harmless garbage
    const int vx = 2 * wr;               // XOR swizzle key (even)
    const _Float16* kfb = kf + l31 * KSTR + 4 * hp + (tg * TILES_PER_TG) * 32 * KSTR;

    for (int ch = 0; ch < SEQ / TC; ++ch) {
        __syncthreads();                  // previous chunk's readers done
        // ---- stage TC t-rows (1 per thread) into kf + swizzled vt ----
        {
            const int tt = tid;
            const int t  = ch * TC + tt;
            const float4 xa  = *(const float4*)(xb + t * 8);
            const float4 xb4 = *(const float4*)(xb + t * 8 + 4);
            float c0 = __cosf(xa.x  + th[0]);
            float c1 = __cosf(xa.y  + th[1]);
            float c2 = __cosf(xa.z  + th[2]);
            float c3 = __cosf(xa.w  + th[3]);
            float c4 = __cosf(xb4.x + th[4]);
            float c5 = __cosf(xb4.y + th[5]);
            float c6 = __cosf(xb4.z + th[6]);
            float c7 = __cosf(xb4.w + th[7]);
            float p1 = c0 * c1, p2 = p1 * c2, p3 = p2 * c3, p4 = p3 * c4;
            float p5 = p4 * c5, p6 = p5 * c6, p7 = p6 * c7;
            float p0 = c1 * c2 * c3 * c4 * c5 * c6 * c7;
            _Float16 h0 = (_Float16)p0, h1 = (_Float16)p1, h2 = (_Float16)p2,
                     h3 = (_Float16)p3, h4 = (_Float16)p4, h5 = (_Float16)p5,
                     h6 = (_Float16)p6, h7 = (_Float16)p7;
            _Float16* krow = kf + tt * KSTR;
            *(f16x4*)(krow)     = (f16x4){h0, h1, h2, h3};
            *(f16x4*)(krow + 4) = (f16x4){h4, h5, h6, h7};
            const int c  = tt >> 1;       // logical word (pair of t)
            const int hb = tt & 1;
            vt[2*(0*512 + (c ^  0)) + hb] = h0;
            vt[2*(1*512 + (c ^  2)) + hb] = h1;
            vt[2*(2*512 + (c ^  4)) + hb] = h2;
            vt[2*(3*512 + (c ^  6)) + hb] = h3;
            vt[2*(4*512 + (c ^  8)) + hb] = h4;
            vt[2*(5*512 + (c ^ 10)) + hb] = h5;
            vt[2*(6*512 + (c ^ 12)) + hb] = h6;
            vt[2*(7*512 + (c ^ 14)) + hb] = h7;
            vt[2*(8*512 + (c ^ 16)) + hb] = (_Float16)1.0f;  // denominator row
        }
        __syncthreads();
        // ---- this wave's 8 t-tiles: QK MFMA -> exp2 -> 4 PV MFMAs ----
#pragma unroll 2
        for (int i = 0; i < TILES_PER_TG; ++i) {
            f16x4 kfrag = *(const f16x4*)(kfb + i * 32 * KSTR);
            f32x16 cc = __builtin_amdgcn_mfma_f32_32x32x8f16(
                kfrag, qfrag, (f32x16){0.f,0.f,0.f,0.f,0.f,0.f,0.f,0.f,
                                       0.f,0.f,0.f,0.f,0.f,0.f,0.f,0.f}, 0, 0, 0);
#pragma unroll
            for (int u = 0; u < 4; ++u) {
                auto lo = __builtin_amdgcn_cvt_pkrtz(EXP2F(cc[4*u+0]), EXP2F(cc[4*u+1]));
                auto hi = __builtin_amdgcn_cvt_pkrtz(EXP2F(cc[4*u+2]), EXP2F(cc[4*u+3]));
                f16x4 pf;
                pf.x = lo.x; pf.y = lo.y; pf.z = hi.x; pf.w = hi.y;
                const int cw   = 16 * (tg * TILES_PER_TG + i) + 4*u + 2*hp;
                const int phys = wr * 512 + (cw ^ vx);        // even ^ even: b64-safe
                f16x4 vfrag = *(const f16x4*)(vt + 2 * phys);
                o = __builtin_amdgcn_mfma_f32_32x32x8f16(pf, vfrag, o, 0, 0, 0);
            }
        }
    }

    // ---- write per-t-group partials (cols 0..8; col 8 = exp-sum) ----
    __syncthreads();                      // all MFMA reads of kf/vt done; alias now
    if (l31 < 9) {
#pragma unroll
        for (int r = 0; r < 16; ++r) {
            const int sloc = sub * 32 + (r & 3) + 8 * (r >> 2) + 4 * hp;
            part[((tg * SROWS) + sloc) * 9 + l31] = o[r];
        }
    }
    __syncthreads();
    // ---- reduce over t-groups (1152 entries > TPB: strided loop!) ----
    for (int idx = tid; idx < SROWS * 9; idx += TPB) {
        const int rr = idx / 9;
        const int w  = idx - rr * 9;
        float sm = 0.f;
#pragma unroll
        for (int g = 0; g < NTG; ++g) sm += part[((g * SROWS) + rr) * 9 + w];
        attn[rr * 9 + w] = sm;
    }
    __syncthreads();
    if (tid < SROWS * 8) {                // normalize in place (col 8 untouched)
        const int rr = tid >> 3;
        const int w  = tid & 7;
        attn[rr * 9 + w] = attn[rr * 9 + w] / attn[rr * 9 + 8];
    }
    __syncthreads();

    // ---- epilogue: swapaxes/reshape scramble + 8x8 combine ----
    if (tid < SROWS) {
        const int e    = tid >> 4;        // wire
        const int nloc = tid & 15;
        const int r    = e * 512 + (S0 >> 3) + nloc;
        float y[8];
#pragma unroll
        for (int c = 0; c < 8; ++c) y[c] = attn[(nloc * 8 + c) * 9 + e];
        float oo[8];
#pragma unroll
        for (int k = 0; k < 8; ++k) {
            float a = bc[k];
#pragma unroll
            for (int c = 0; c < 8; ++c) a += y[c] * wc[k * 8 + c];
            oo[k] = a;
        }
        float4* op = (float4*)(out + ((size_t)b * SEQ + r) * 8);
        op[0] = make_float4(oo[0], oo[1], oo[2], oo[3]);
        op[1] = make_float4(oo[4], oo[5], oo[6], oo[7]);
    }
}

extern "C" void kernel_launch(void* const* d_in, const int* in_sizes, int n_in,
                              void* d_out, int out_size, void* d_ws, size_t ws_size,
                              hipStream_t stream)
{
    const float* x  = (const float*)d_in[0];
    const float* th = (const float*)d_in[1];
    const float* wc = (const float*)d_in[2];
    const float* bc = (const float*)d_in[3];
    float* out = (float*)d_out;

    qattn_kernel<<<dim3(NB * (SEQ / SROWS)), dim3(TPB), 0, stream>>>(x, th, wc, bc, out);
}

// Round 11
// 91.234 us; speedup vs baseline: 2.7322x; 1.0567x over previous
//
#include <hip/hip_runtime.h>
#include <math.h>

// Closed form derived from the reference:
//   q[n,0] = prod_{v=1..7} cos(x[n,v]+theta[v])
//   q[n,w] = prod_{v=0..w} cos(x[n,v]+theta[v])   (w = 1..7)
// Attention with E=8, no-max softmax (|score| <= 8/sqrt2), output scramble:
//   final[b,r,k] = sum_c att[b,(r%512)*8+c, r/512] * W[k,c] + bias[k].
//
// R10: VALU-glue trim. R9's XOR-swizzled vt cost ~14 VALU/tile of per-lane
//      address math. Replace with padded-stride vt (row stride 1028 f16;
//      514 words % 32 banks = 2 -> lane w hits bank 2w+c, <=2-way = free):
//      vfrag reads become base + immediate offsets (i*64+u*16 B), staging
//      write is vt[w*1028+tt]. Lanes w>8 broadcast-read the ones row.
//      pf packed via union pun (no movs). Structure from R9: TPB=1024 =
//      4 s-subtiles x 4 t-groups, 2 blocks/CU; 32x32x8 MFMA layout identity
//      (QK^T C-regs [4u..4u+3] ARE the PV A-frag for t-slice u).

#define SEQ   4096
#define NB    16
#define SROWS 128          // s-rows per block (4 subtiles x 32)
#define TPB   1024
#define NTG   4            // t-groups
#define TC    1024         // t rows staged per chunk
#define TILES_PER_TG 8     // (TC/32)/NTG
#define KSTR  12           // kf row stride in f16 (24 B)
#define VSTR  1028         // vt row stride in f16 (bank-offset 2 per row)

typedef _Float16 f16x4  __attribute__((ext_vector_type(4)));
typedef float    f32x16 __attribute__((ext_vector_type(16)));
typedef __fp16   hf2    __attribute__((ext_vector_type(2)));

#if __has_builtin(__builtin_amdgcn_exp2f)
#define EXP2F(x) __builtin_amdgcn_exp2f(x)
#else
#define EXP2F(x) exp2f(x)
#endif

__global__ __launch_bounds__(TPB, 8)   // VGPR cap 64; 2 blocks/CU -> 32 waves/CU
void qattn_kernel(const float* __restrict__ x, const float* __restrict__ theta,
                  const float* __restrict__ wc, const float* __restrict__ bc,
                  float* __restrict__ out)
{
    __shared__ __align__(16) _Float16 kf[TC * KSTR];  // 24576 B: [t][8 f16 + 4 pad]
    __shared__ __align__(16) _Float16 vt[9 * VSTR];   // 18504 B: [w][t], w=8 = ones
    // after the last MFMA barrier these are re-used:
    float* part = (float*)kf;            // [NTG][SROWS][9] = 18432 B
    float* attn = (float*)vt;            // [SROWS][9]      =  4608 B

    const int tid  = threadIdx.x;
    const int lane = tid & 63;
    const int wv   = tid >> 6;           // 0..15
    const int sub  = wv & 3;             // s-subtile (32 rows)
    const int tg   = wv >> 2;            // t-group
    const int l31  = lane & 31;
    const int hp   = lane >> 5;

    const int b  = blockIdx.x >> 5;
    const int S0 = (blockIdx.x & 31) * SROWS;
    const float* xb = x + (size_t)b * SEQ * 8;

    float th[8];
#pragma unroll
    for (int w = 0; w < 8; ++w) th[w] = theta[w];

    // ---- Q fragment (B operand of QK): B[k=w=4hp+j][n=s=l31], scaled ----
    f16x4 qfrag;
    {
        const int s = S0 + sub * 32 + l31;
        const float4 xa  = *(const float4*)(xb + s * 8);
        const float4 xb4 = *(const float4*)(xb + s * 8 + 4);
        float c0 = __cosf(xa.x  + th[0]);
        float c1 = __cosf(xa.y  + th[1]);
        float c2 = __cosf(xa.z  + th[2]);
        float c3 = __cosf(xa.w  + th[3]);
        float c4 = __cosf(xb4.x + th[4]);
        float c5 = __cosf(xb4.y + th[5]);
        float c6 = __cosf(xb4.z + th[6]);
        float c7 = __cosf(xb4.w + th[7]);
        float p1 = c0 * c1, p2 = p1 * c2, p3 = p2 * c3, p4 = p3 * c4;
        float p5 = p4 * c5, p6 = p5 * c6, p7 = p6 * c7;
        float p0 = c1 * c2 * c3 * c4 * c5 * c6 * c7;
        const float sc = 0.70710678118654752f * 1.44269504088896341f;
        if (hp == 0)
            qfrag = (f16x4){(_Float16)(p0*sc), (_Float16)(p1*sc),
                            (_Float16)(p2*sc), (_Float16)(p3*sc)};
        else
            qfrag = (f16x4){(_Float16)(p4*sc), (_Float16)(p5*sc),
                            (_Float16)(p6*sc), (_Float16)(p7*sc)};
    }

    f32x16 o = {0.f,0.f,0.f,0.f,0.f,0.f,0.f,0.f,0.f,0.f,0.f,0.f,0.f,0.f,0.f,0.f};

    const int wr = (l31 < 8) ? l31 : 8;  // lanes w>=8 broadcast-read ones row
    const _Float16* kfb = kf + l31 * KSTR + 4 * hp + (tg * TILES_PER_TG) * 32 * KSTR;
    const _Float16* vbb = vt + wr * VSTR + 4 * hp + tg * (TILES_PER_TG * 32);

    for (int ch = 0; ch < SEQ / TC; ++ch) {
        __syncthreads();                  // previous chunk's readers done
        // ---- stage TC t-rows (1 per thread) into kf + padded vt ----
        {
            const int tt = tid;
            const int t  = ch * TC + tt;
            const float4 xa  = *(const float4*)(xb + t * 8);
            const float4 xb4 = *(const float4*)(xb + t * 8 + 4);
            float c0 = __cosf(xa.x  + th[0]);
            float c1 = __cosf(xa.y  + th[1]);
            float c2 = __cosf(xa.z  + th[2]);
            float c3 = __cosf(xa.w  + th[3]);
            float c4 = __cosf(xb4.x + th[4]);
            float c5 = __cosf(xb4.y + th[5]);
            float c6 = __cosf(xb4.z + th[6]);
            float c7 = __cosf(xb4.w + th[7]);
            float p1 = c0 * c1, p2 = p1 * c2, p3 = p2 * c3, p4 = p3 * c4;
            float p5 = p4 * c5, p6 = p5 * c6, p7 = p6 * c7;
            float p0 = c1 * c2 * c3 * c4 * c5 * c6 * c7;
            _Float16 h0 = (_Float16)p0, h1 = (_Float16)p1, h2 = (_Float16)p2,
                     h3 = (_Float16)p3, h4 = (_Float16)p4, h5 = (_Float16)p5,
                     h6 = (_Float16)p6, h7 = (_Float16)p7;
            _Float16* krow = kf + tt * KSTR;
            *(f16x4*)(krow)     = (f16x4){h0, h1, h2, h3};
            *(f16x4*)(krow + 4) = (f16x4){h4, h5, h6, h7};
            vt[0 * VSTR + tt] = h0;
            vt[1 * VSTR + tt] = h1;
            vt[2 * VSTR + tt] = h2;
            vt[3 * VSTR + tt] = h3;
            vt[4 * VSTR + tt] = h4;
            vt[5 * VSTR + tt] = h5;
            vt[6 * VSTR + tt] = h6;
            vt[7 * VSTR + tt] = h7;
            vt[8 * VSTR + tt] = (_Float16)1.0f;   // denominator row
        }
        __syncthreads();
        // ---- this wave's 8 t-tiles: QK MFMA -> exp2 -> 4 PV MFMAs ----
#pragma unroll 4
        for (int i = 0; i < TILES_PER_TG; ++i) {
            f16x4 kfrag = *(const f16x4*)(kfb + i * 32 * KSTR);
            f32x16 cc = __builtin_amdgcn_mfma_f32_32x32x8f16(
                kfrag, qfrag, (f32x16){0.f,0.f,0.f,0.f,0.f,0.f,0.f,0.f,
                                       0.f,0.f,0.f,0.f,0.f,0.f,0.f,0.f}, 0, 0, 0);
#pragma unroll
            for (int u = 0; u < 4; ++u) {
                union { hf2 h[2]; f16x4 v; } pu;
                pu.h[0] = __builtin_amdgcn_cvt_pkrtz(EXP2F(cc[4*u+0]), EXP2F(cc[4*u+1]));
                pu.h[1] = __builtin_amdgcn_cvt_pkrtz(EXP2F(cc[4*u+2]), EXP2F(cc[4*u+3]));
                // vfrag: base + compile-time offset (i*32 + u*8 f16)
                f16x4 vfrag = *(const f16x4*)(vbb + i * 32 + u * 8);
                o = __builtin_amdgcn_mfma_f32_32x32x8f16(pu.v, vfrag, o, 0, 0, 0);
            }
        }
    }

    // ---- write per-t-group partials (cols 0..8; col 8 = exp-sum) ----
    __syncthreads();                      // all MFMA reads of kf/vt done; alias now
    if (l31 < 9) {
#pragma unroll
        for (int r = 0; r < 16; ++r) {
            const int sloc = sub * 32 + (r & 3) + 8 * (r >> 2) + 4 * hp;
            part[((tg * SROWS) + sloc) * 9 + l31] = o[r];
        }
    }
    __syncthreads();
    // ---- reduce over t-groups (1152 entries > TPB: strided loop!) ----
    for (int idx = tid; idx < SROWS * 9; idx += TPB) {
        const int rr = idx / 9;
        const int w  = idx - rr * 9;
        float sm = 0.f;
#pragma unroll
        for (int g = 0; g < NTG; ++g) sm += part[((g * SROWS) + rr) * 9 + w];
        attn[rr * 9 + w] = sm;
    }
    __syncthreads();
    if (tid < SROWS * 8) {                // normalize in place (col 8 untouched)
        const int rr = tid >> 3;
        const int w  = tid & 7;
        attn[rr * 9 + w] = attn[rr * 9 + w] / attn[rr * 9 + 8];
    }
    __syncthreads();

    // ---- epilogue: swapaxes/reshape scramble + 8x8 combine ----
    if (tid < SROWS) {
        const int e    = tid >> 4;        // wire
        const int nloc = tid & 15;
        const int r    = e * 512 + (S0 >> 3) + nloc;
        float y[8];
#pragma unroll
        for (int c = 0; c < 8; ++c) y[c] = attn[(nloc * 8 + c) * 9 + e];
        float oo[8];
#pragma unroll
        for (int k = 0; k < 8; ++k) {
            float a = bc[k];
#pragma unroll
            for (int c = 0; c < 8; ++c) a += y[c] * wc[k * 8 + c];
            oo[k] = a;
        }
        float4* op = (float4*)(out + ((size_t)b * SEQ + r) * 8);
        op[0] = make_float4(oo[0], oo[1], oo[2], oo[3]);
        op[1] = make_float4(oo[4], oo[5], oo[6], oo[7]);
    }
}

extern "C" void kernel_launch(void* const* d_in, const int* in_sizes, int n_in,
                              void* d_out, int out_size, void* d_ws, size_t ws_size,
                              hipStream_t stream)
{
    const float* x  = (const float*)d_in[0];
    const float* th = (const float*)d_in[1];
    const float* wc = (const float*)d_in[2];
    const float* bc = (const float*)d_in[3];
    float* out = (float*)d_out;

    qattn_kernel<<<dim3(NB * (SEQ / SROWS)), dim3(TPB), 0, stream>>>(x, th, wc, bc, out);
}

// Round 12
// 90.863 us; speedup vs baseline: 2.7433x; 1.0041x over previous
//
#include <hip/hip_runtime.h>
#include <math.h>

// Closed form derived from the reference:
//   q[n,0] = prod_{v=1..7} cos(x[n,v]+theta[v])
//   q[n,w] = prod_{v=0..w} cos(x[n,v]+theta[v])   (w = 1..7)
// Attention with E=8, no-max softmax (|score| <= 8/sqrt2), output scramble:
//   final[b,r,k] = sum_c att[b,(r%512)*8+c, r/512] * W[k,c] + bias[k].
//
// R11: staging prefetch. R10's chunk loop serialized global-load -> cos ->
//      ds_write -> barrier 4x with nothing in flight. Now x(ch+1) is loaded
//      into VGPRs right after the staging barrier (in flight across the 8-tile
//      MFMA loop), cos computed while waiting on the readers-done barrier,
//      only ds_writes between barriers. Ones row hoisted out of the loop.
//      Structure from R10: TPB=1024 = 4 s-subtiles x 4 t-groups, 2 blocks/CU;
//      padded-stride vt (VSTR=1028); 32x32x8 MFMA layout identity
//      (QK^T C-regs [4u..4u+3] ARE the PV A-frag for t-slice u).

#define SEQ   4096
#define NB    16
#define SROWS 128          // s-rows per block (4 subtiles x 32)
#define TPB   1024
#define NTG   4            // t-groups
#define TC    1024         // t rows staged per chunk
#define NCH   (SEQ / TC)   // 4 chunks
#define TILES_PER_TG 8     // (TC/32)/NTG
#define KSTR  12           // kf row stride in f16 (24 B)
#define VSTR  1028         // vt row stride in f16 (bank-offset 2 per row)

typedef _Float16 f16x4  __attribute__((ext_vector_type(4)));
typedef float    f32x16 __attribute__((ext_vector_type(16)));
typedef __fp16   hf2    __attribute__((ext_vector_type(2)));

#if __has_builtin(__builtin_amdgcn_exp2f)
#define EXP2F(x) __builtin_amdgcn_exp2f(x)
#else
#define EXP2F(x) exp2f(x)
#endif

__global__ __launch_bounds__(TPB, 8)   // VGPR cap 64; 2 blocks/CU -> 32 waves/CU
void qattn_kernel(const float* __restrict__ x, const float* __restrict__ theta,
                  const float* __restrict__ wc, const float* __restrict__ bc,
                  float* __restrict__ out)
{
    __shared__ __align__(16) _Float16 kf[TC * KSTR];  // 24576 B: [t][8 f16 + 4 pad]
    __shared__ __align__(16) _Float16 vt[9 * VSTR];   // 18504 B: [w][t], w=8 = ones
    // after the last MFMA barrier these are re-used:
    float* part = (float*)kf;            // [NTG][SROWS][9] = 18432 B
    float* attn = (float*)vt;            // [SROWS][9]      =  4608 B

    const int tid  = threadIdx.x;
    const int lane = tid & 63;
    const int wv   = tid >> 6;           // 0..15
    const int sub  = wv & 3;             // s-subtile (32 rows)
    const int tg   = wv >> 2;            // t-group
    const int l31  = lane & 31;
    const int hp   = lane >> 5;

    const int b  = blockIdx.x >> 5;
    const int S0 = (blockIdx.x & 31) * SROWS;
    const float* xb = x + (size_t)b * SEQ * 8;

    float th[8];
#pragma unroll
    for (int w = 0; w < 8; ++w) th[w] = theta[w];

    // ones (denominator) row: constant across chunks, write once.
    // max vt row-8 index read is 1023 < 1024, so TPB writes cover it.
    vt[8 * VSTR + tid] = (_Float16)1.0f;

    // ---- Q fragment (B operand of QK): B[k=w=4hp+j][n=s=l31], scaled ----
    f16x4 qfrag;
    {
        const int s = S0 + sub * 32 + l31;
        const float4 xa  = *(const float4*)(xb + s * 8);
        const float4 xb4 = *(const float4*)(xb + s * 8 + 4);
        float c0 = __cosf(xa.x  + th[0]);
        float c1 = __cosf(xa.y  + th[1]);
        float c2 = __cosf(xa.z  + th[2]);
        float c3 = __cosf(xa.w  + th[3]);
        float c4 = __cosf(xb4.x + th[4]);
        float c5 = __cosf(xb4.y + th[5]);
        float c6 = __cosf(xb4.z + th[6]);
        float c7 = __cosf(xb4.w + th[7]);
        float p1 = c0 * c1, p2 = p1 * c2, p3 = p2 * c3, p4 = p3 * c4;
        float p5 = p4 * c5, p6 = p5 * c6, p7 = p6 * c7;
        float p0 = c1 * c2 * c3 * c4 * c5 * c6 * c7;
        const float sc = 0.70710678118654752f * 1.44269504088896341f;
        if (hp == 0)
            qfrag = (f16x4){(_Float16)(p0*sc), (_Float16)(p1*sc),
                            (_Float16)(p2*sc), (_Float16)(p3*sc)};
        else
            qfrag = (f16x4){(_Float16)(p4*sc), (_Float16)(p5*sc),
                            (_Float16)(p6*sc), (_Float16)(p7*sc)};
    }

    f32x16 o = {0.f,0.f,0.f,0.f,0.f,0.f,0.f,0.f,0.f,0.f,0.f,0.f,0.f,0.f,0.f,0.f};

    const int wr = (l31 < 8) ? l31 : 8;  // lanes w>=8 broadcast-read ones row
    const _Float16* kfb = kf + l31 * KSTR + 4 * hp + (tg * TILES_PER_TG) * 32 * KSTR;
    const _Float16* vbb = vt + wr * VSTR + 4 * hp + tg * (TILES_PER_TG * 32);

    // prefetch chunk 0's x rows into registers
    float4 pxa = *(const float4*)(xb + tid * 8);
    float4 pxb = *(const float4*)(xb + tid * 8 + 4);

    for (int ch = 0; ch < NCH; ++ch) {
        // ---- cos/f16 from prefetched regs (overlaps the barrier wait) ----
        float c0 = __cosf(pxa.x + th[0]);
        float c1 = __cosf(pxa.y + th[1]);
        float c2 = __cosf(pxa.z + th[2]);
        float c3 = __cosf(pxa.w + th[3]);
        float c4 = __cosf(pxb.x + th[4]);
        float c5 = __cosf(pxb.y + th[5]);
        float c6 = __cosf(pxb.z + th[6]);
        float c7 = __cosf(pxb.w + th[7]);
        float p1 = c0 * c1, p2 = p1 * c2, p3 = p2 * c3, p4 = p3 * c4;
        float p5 = p4 * c5, p6 = p5 * c6, p7 = p6 * c7;
        float p0 = c1 * c2 * c3 * c4 * c5 * c6 * c7;
        _Float16 h0 = (_Float16)p0, h1 = (_Float16)p1, h2 = (_Float16)p2,
                 h3 = (_Float16)p3, h4 = (_Float16)p4, h5 = (_Float16)p5,
                 h6 = (_Float16)p6, h7 = (_Float16)p7;
        __syncthreads();                  // previous chunk's readers done
        {
            _Float16* krow = kf + tid * KSTR;
            *(f16x4*)(krow)     = (f16x4){h0, h1, h2, h3};
            *(f16x4*)(krow + 4) = (f16x4){h4, h5, h6, h7};
            vt[0 * VSTR + tid] = h0;
            vt[1 * VSTR + tid] = h1;
            vt[2 * VSTR + tid] = h2;
            vt[3 * VSTR + tid] = h3;
            vt[4 * VSTR + tid] = h4;
            vt[5 * VSTR + tid] = h5;
            vt[6 * VSTR + tid] = h6;
            vt[7 * VSTR + tid] = h7;
        }
        __syncthreads();
        // ---- prefetch next chunk's x (in flight across the MFMA loop) ----
        {
            const int nt = ((ch + 1 < NCH) ? (ch + 1) * TC : ch * TC) + tid;
            pxa = *(const float4*)(xb + nt * 8);
            pxb = *(const float4*)(xb + nt * 8 + 4);
        }
        // ---- this wave's 8 t-tiles: QK MFMA -> exp2 -> 4 PV MFMAs ----
#pragma unroll 4
        for (int i = 0; i < TILES_PER_TG; ++i) {
            f16x4 kfrag = *(const f16x4*)(kfb + i * 32 * KSTR);
            f32x16 cc = __builtin_amdgcn_mfma_f32_32x32x8f16(
                kfrag, qfrag, (f32x16){0.f,0.f,0.f,0.f,0.f,0.f,0.f,0.f,
                                       0.f,0.f,0.f,0.f,0.f,0.f,0.f,0.f}, 0, 0, 0);
#pragma unroll
            for (int u = 0; u < 4; ++u) {
                union { hf2 h[2]; f16x4 v; } pu;
                pu.h[0] = __builtin_amdgcn_cvt_pkrtz(EXP2F(cc[4*u+0]), EXP2F(cc[4*u+1]));
                pu.h[1] = __builtin_amdgcn_cvt_pkrtz(EXP2F(cc[4*u+2]), EXP2F(cc[4*u+3]));
                // vfrag: base + compile-time offset (i*32 + u*8 f16)
                f16x4 vfrag = *(const f16x4*)(vbb + i * 32 + u * 8);
                o = __builtin_amdgcn_mfma_f32_32x32x8f16(pu.v, vfrag, o, 0, 0, 0);
            }
        }
    }

    // ---- write per-t-group partials (cols 0..8; col 8 = exp-sum) ----
    __syncthreads();                      // all MFMA reads of kf/vt done; alias now
    if (l31 < 9) {
#pragma unroll
        for (int r = 0; r < 16; ++r) {
            const int sloc = sub * 32 + (r & 3) + 8 * (r >> 2) + 4 * hp;
            part[((tg * SROWS) + sloc) * 9 + l31] = o[r];
        }
    }
    __syncthreads();
    // ---- reduce over t-groups (1152 entries > TPB: strided loop!) ----
    for (int idx = tid; idx < SROWS * 9; idx += TPB) {
        const int rr = idx / 9;
        const int w  = idx - rr * 9;
        float sm = 0.f;
#pragma unroll
        for (int g = 0; g < NTG; ++g) sm += part[((g * SROWS) + rr) * 9 + w];
        attn[rr * 9 + w] = sm;
    }
    __syncthreads();
    if (tid < SROWS * 8) {                // normalize in place (col 8 untouched)
        const int rr = tid >> 3;
        const int w  = tid & 7;
        attn[rr * 9 + w] = attn[rr * 9 + w] / attn[rr * 9 + 8];
    }
    __syncthreads();

    // ---- epilogue: swapaxes/reshape scramble + 8x8 combine ----
    if (tid < SROWS) {
        const int e    = tid >> 4;        // wire
        const int nloc = tid & 15;
        const int r    = e * 512 + (S0 >> 3) + nloc;
        float y[8];
#pragma unroll
        for (int c = 0; c < 8; ++c) y[c] = attn[(nloc * 8 + c) * 9 + e];
        float oo[8];
#pragma unroll
        for (int k = 0; k < 8; ++k) {
            float a = bc[k];
#pragma unroll
            for (int c = 0; c < 8; ++c) a += y[c] * wc[k * 8 + c];
            oo[k] = a;
        }
        float4* op = (float4*)(out + ((size_t)b * SEQ + r) * 8);
        op[0] = make_float4(oo[0], oo[1], oo[2], oo[3]);
        op[1] = make_float4(oo[4], oo[5], oo[6], oo[7]);
    }
}

extern "C" void kernel_launch(void* const* d_in, const int* in_sizes, int n_in,
                              void* d_out, int out_size, void* d_ws, size_t ws_size,
                              hipStream_t stream)
{
    const float* x  = (const float*)d_in[0];
    const float* th = (const float*)d_in[1];
    const float* wc = (const float*)d_in[2];
    const float* bc = (const float*)d_in[3];
    float* out = (float*)d_out;

    qattn_kernel<<<dim3(NB * (SEQ / SROWS)), dim3(TPB), 0, stream>>>(x, th, wc, bc, out);
}